// Round 1
// baseline (6252.057 us; speedup 1.0000x reference)
//
#include <hip/hip_runtime.h>
#include <hip/hip_bf16.h>

#define B_ 4096
#define T_ 24
#define F_ 12
#define H_ 512
#define GH_ 2048   // 4*H
#define ZW_ 6400   // F*H + 256

typedef __attribute__((ext_vector_type(8))) short short8;
typedef __attribute__((ext_vector_type(4))) float f32x4;

__device__ __forceinline__ short f2bf(float f) {
    union { float f; unsigned int u; } v; v.f = f;
    unsigned int u = v.u;
    unsigned int r = (u + 0x7FFFu + ((u >> 16) & 1u)) >> 16;
    return (short)r;
}
__device__ __forceinline__ float bf2f(short b) {
    union { unsigned int u; float f; } v; v.u = ((unsigned int)(unsigned short)b) << 16;
    return v.f;
}
__device__ __forceinline__ float fastrcp(float x) { return __builtin_amdgcn_rcpf(x); }
__device__ __forceinline__ float sigm(float x) { return fastrcp(1.f + __expf(-x)); }
__device__ __forceinline__ float tanh_(float x) { return 1.f - 2.f * fastrcp(__expf(2.f * x) + 1.f); }

// ---------------------------------------------------------------- convert
__global__ void k_convert(const float* Whh, const float* dW1, const float* dW2,
                          const float* bih, const float* bhh,
                          const float* sW1, const float* sW2, const float* sW3,
                          short* oWhh, short* odW1, short* odW2, float* obias,
                          float* sW1T, float* sW2T, float* sW3T) {
    const int N1 = F_ * GH_ * H_;          // 12,582,912
    const int N2 = 1024 * ZW_;             // 6,553,600
    const int N3 = 1024 * 1024;
    const int NB = F_ * GH_;
    int idx = blockIdx.x * blockDim.x + threadIdx.x;
    int stride = gridDim.x * blockDim.x;
    for (int i = idx; i < N1; i += stride) oWhh[i] = f2bf(Whh[i]);
    for (int i = idx; i < N2; i += stride) odW1[i] = f2bf(dW1[i]);
    for (int i = idx; i < N3; i += stride) odW2[i] = f2bf(dW2[i]);
    for (int i = idx; i < NB; i += stride) obias[i] = bih[i] + bhh[i];
    for (int i = idx; i < 64 * 256; i += stride) {      // sW1T[i][t] = sW1[t][i]
        int r = i >> 8, t = i & 255;
        sW1T[i] = sW1[t * 64 + r];
    }
    for (int i = idx; i < 256 * 256; i += stride) {
        int r = i >> 8, t = i & 255;
        sW2T[i] = sW2[t * 256 + r];
        sW3T[i] = sW3[t * 256 + r];
    }
}

// ---------------------------------------------------------------- LSTM
// grid 768 (12 features x 64 batch-tiles of 64 rows), 512 threads (8 waves).
// h double-buffered bf16 in LDS (swizzled); c in registers; one barrier/step.
__global__ __launch_bounds__(512, 2)
void k_lstm(const short* __restrict__ Whh,   // [F][2048][512] bf16
            const float* __restrict__ Wih,   // [F][2048][2]
            const float* __restrict__ bias,  // [F][2048] (b_ih+b_hh)
            const float* __restrict__ tfeat, // [B][T][F]
            const float* __restrict__ tmask,
            const float* __restrict__ h0,    // [F][B][H]
            const float* __restrict__ c0,
            short* __restrict__ Z)           // [B][6400] bf16
{
    __shared__ __align__(16) short hbuf[2][64 * 512];
    __shared__ float xv[2][64], xm[2][64];

    int bid = blockIdx.x;
    int wg = (bid & 7) * 96 + (bid >> 3);    // XCD swizzle (768 = 8*96, bijective)
    int f = wg >> 6;
    int b0 = (wg & 63) * 64;
    int tid = threadIdx.x;
    int w = tid >> 6;
    int l = tid & 63;
    int l15 = l & 15, lq = l >> 4;

    // stage h0 -> hbuf[0] (bf16, swizzled)
    {
        int row = tid >> 3, cg = (tid & 7) * 64;
        const float* src = h0 + ((size_t)f * B_ + b0 + row) * H_ + cg;
        #pragma unroll
        for (int i = 0; i < 64; i += 8) {
            short tmp[8];
            #pragma unroll
            for (int j = 0; j < 8; j++) tmp[j] = f2bf(src[i + j]);
            int elem = (row * 512 + cg + i) ^ ((row & 7) << 3);
            *(short8*)&hbuf[0][elem] = *(short8*)tmp;
        }
    }
    if (tid < 64)        xv[0][tid]      = tfeat[(size_t)(b0 + tid) * (T_ * F_) + f];
    else if (tid < 128)  xm[0][tid - 64] = tmask[(size_t)(b0 + tid - 64) * (T_ * F_) + f];

    // c0 -> registers, matching MFMA D layout: c[s][r][p]
    float c[4][4][4];
    #pragma unroll
    for (int s = 0; s < 4; s++) {
        int j = w * 64 + s * 16 + l15;
        #pragma unroll
        for (int r = 0; r < 4; r++) {
            const float* cp = c0 + ((size_t)f * B_ + b0 + r * 16 + lq * 4) * H_ + j;
            #pragma unroll
            for (int p = 0; p < 4; p++) c[s][r][p] = cp[(size_t)p * H_];
        }
    }
    __syncthreads();

    const short* Wf    = Whh + (size_t)f * GH_ * H_;
    const float* Wihf  = Wih + (size_t)f * GH_ * 2;
    const float* biasf = bias + (size_t)f * GH_;

    #pragma unroll 1
    for (int t = 0; t < T_; t++) {
        int rb = t & 1, wb = rb ^ 1;
        // prefetch x(t+1) into the other buffer (no extra barrier needed)
        if (t < T_ - 1) {
            if (tid < 64)       xv[wb][tid]      = tfeat[(size_t)(b0 + tid) * (T_ * F_) + (t + 1) * F_ + f];
            else if (tid < 128) xm[wb][tid - 64] = tmask[(size_t)(b0 + tid - 64) * (T_ * F_) + (t + 1) * F_ + f];
        }
        // hoist x for this lane's 16 rows
        float xvr[4][4], xmr[4][4];
        #pragma unroll
        for (int r = 0; r < 4; r++)
            #pragma unroll
            for (int p = 0; p < 4; p++) {
                int row = r * 16 + lq * 4 + p;
                xvr[r][p] = xv[rb][row];
                xmr[r][p] = xm[rb][row];
            }

        #pragma unroll 1
        for (int s = 0; s < 4; s++) {
            int j = w * 64 + s * 16 + l15;
            // init acc with bias + x-part (all in fp32)
            f32x4 acc[4][4];   // [gate][rowfrag]
            #pragma unroll
            for (int g = 0; g < 4; g++) {
                int col = g * 512 + j;
                float bsum = biasf[col];
                float wx0 = Wihf[col * 2], wx1 = Wihf[col * 2 + 1];
                #pragma unroll
                for (int r = 0; r < 4; r++)
                    #pragma unroll
                    for (int p = 0; p < 4; p++)
                        acc[g][r][p] = bsum + wx0 * xvr[r][p] + wx1 * xmr[r][p];
            }
            // K loop: 512 = 16 x 32
            #pragma unroll
            for (int kk = 0; kk < 16; kk++) {
                int k = kk * 32 + lq * 8;
                short8 a[4], bfr[4];
                #pragma unroll
                for (int r = 0; r < 4; r++) {
                    int row = r * 16 + l15;
                    int elem = (row * 512 + k) ^ ((row & 7) << 3);
                    a[r] = *(const short8*)&hbuf[rb][elem];
                }
                #pragma unroll
                for (int g = 0; g < 4; g++)
                    bfr[g] = *(const short8*)(Wf + (size_t)(g * 512 + j) * H_ + k);
                #pragma unroll
                for (int g = 0; g < 4; g++)
                    #pragma unroll
                    for (int r = 0; r < 4; r++)
                        acc[g][r] = __builtin_amdgcn_mfma_f32_16x16x32_bf16(a[r], bfr[g], acc[g][r], 0, 0, 0);
            }
            // cell update + h write (fp32 nonlinearity, bf16 h)
            #pragma unroll
            for (int r = 0; r < 4; r++)
                #pragma unroll
                for (int p = 0; p < 4; p++) {
                    float iv = acc[0][r][p], fv = acc[1][r][p];
                    float gv = acc[2][r][p], ov = acc[3][r][p];
                    float cn = sigm(fv) * c[s][r][p] + sigm(iv) * tanh_(gv);
                    c[s][r][p] = cn;
                    float hn = sigm(ov) * tanh_(cn);
                    int row = r * 16 + lq * 4 + p;
                    int elem = (row * 512 + j) ^ ((row & 7) << 3);
                    hbuf[wb][elem] = f2bf(hn);
                }
        }
        __syncthreads();
    }

    // final h (in hbuf[0], since T even) -> Z columns [f*512, f*512+512)
    {
        int row = tid >> 3, cg = (tid & 7) * 64;
        short* dst = Z + (size_t)(b0 + row) * ZW_ + f * H_ + cg;
        #pragma unroll
        for (int i = 0; i < 64; i += 8) {
            int elem = (row * 512 + cg + i) ^ ((row & 7) << 3);
            *(short8*)(dst + i) = *(const short8*)&hbuf[0][elem];
        }
    }
}

// ---------------------------------------------------------------- static MLP
// one row per block, 256 threads; weights pre-transposed for coalescing
__global__ void k_static(const float* __restrict__ X,
                         const float* __restrict__ sW1T, const float* __restrict__ sb1,
                         const float* __restrict__ sW2T, const float* __restrict__ sb2,
                         const float* __restrict__ sW3T, const float* __restrict__ sb3,
                         short* __restrict__ Z) {
    __shared__ float xs[64], s1[256], s2[256];
    int row = blockIdx.x, tid = threadIdx.x;
    if (tid < 64) xs[tid] = X[row * 64 + tid];
    __syncthreads();
    float a = sb1[tid];
    for (int i = 0; i < 64; i++) a += xs[i] * sW1T[i * 256 + tid];
    s1[tid] = fmaxf(a, 0.f);
    __syncthreads();
    a = sb2[tid];
    for (int i = 0; i < 256; i++) a += s1[i] * sW2T[i * 256 + tid];
    s2[tid] = fmaxf(a, 0.f);
    __syncthreads();
    a = sb3[tid];
    for (int i = 0; i < 256; i++) a += s2[i] * sW3T[i * 256 + tid];
    Z[(size_t)row * ZW_ + F_ * H_ + tid] = f2bf(fmaxf(a, 0.f));
}

// ---------------------------------------------------------------- GEMM + bias + relu
// C[M,N] = relu(A[M,K] @ W[N,K]^T + bias), all bf16 except bias; 128x128 tile
__global__ __launch_bounds__(256, 2)
void k_gemm_relu(const short* __restrict__ A, const short* __restrict__ W,
                 const float* __restrict__ bias, short* __restrict__ C,
                 int M, int N, int K) {
    __shared__ __align__(16) short at[128 * 128];
    int tid = threadIdx.x;
    int wid = tid >> 6, l = tid & 63, l15 = l & 15, lq = l >> 4;
    int wm = wid >> 1, wn = wid & 1;
    int mb = blockIdx.x * 128, nb = blockIdx.y * 128;
    f32x4 acc[4][4];   // [colfrag][rowfrag]
    #pragma unroll
    for (int n = 0; n < 4; n++)
        #pragma unroll
        for (int r = 0; r < 4; r++)
            acc[n][r] = (f32x4){0.f, 0.f, 0.f, 0.f};

    #pragma unroll 1
    for (int kc = 0; kc < K; kc += 128) {
        {   // stage A tile 128x128 bf16 (swizzled)
            int row = tid >> 1, off = (tid & 1) * 64;
            const short* src = A + (size_t)(mb + row) * K + kc + off;
            #pragma unroll
            for (int i = 0; i < 64; i += 8) {
                short8 v = *(const short8*)(src + i);
                int elem = (row * 128 + off + i) ^ ((row & 7) << 3);
                *(short8*)&at[elem] = v;
            }
        }
        __syncthreads();
        #pragma unroll
        for (int kk = 0; kk < 4; kk++) {
            int k = kk * 32 + lq * 8;
            short8 a[4], bfr[4];
            #pragma unroll
            for (int r = 0; r < 4; r++) {
                int row = wm * 64 + 16 * r + l15;
                int elem = (row * 128 + k) ^ ((row & 7) << 3);
                a[r] = *(const short8*)&at[elem];
            }
            #pragma unroll
            for (int n = 0; n < 4; n++)
                bfr[n] = *(const short8*)(W + (size_t)(nb + wn * 64 + 16 * n + l15) * K + kc + k);
            #pragma unroll
            for (int n = 0; n < 4; n++)
                #pragma unroll
                for (int r = 0; r < 4; r++)
                    acc[n][r] = __builtin_amdgcn_mfma_f32_16x16x32_bf16(a[r], bfr[n], acc[n][r], 0, 0, 0);
        }
        __syncthreads();
    }
    #pragma unroll
    for (int n = 0; n < 4; n++) {
        int col = nb + wn * 64 + 16 * n + l15;
        float bv = bias[col];
        #pragma unroll
        for (int r = 0; r < 4; r++)
            #pragma unroll
            for (int p = 0; p < 4; p++) {
                int row = mb + wm * 64 + 16 * r + lq * 4 + p;
                C[(size_t)row * N + col] = f2bf(fmaxf(acc[n][r][p] + bv, 0.f));
            }
    }
}

// ---------------------------------------------------------------- head layer 3 + BCE partials
__global__ void k_head3(const short* __restrict__ Z2, const float* __restrict__ W3,
                        const float* __restrict__ b3, const float* __restrict__ tgt,
                        float* __restrict__ out, float* __restrict__ lsum) {
    __shared__ float ls[32];
    int tid = threadIdx.x, wv = tid >> 6, l = tid & 63;
    int rsub = l >> 3, ks = l & 7;
    int row = blockIdx.x * 32 + wv * 8 + rsub;
    const short* z = Z2 + (size_t)row * 1024 + ks * 128;
    const float* w0 = W3 + ks * 128;
    const float* w1 = W3 + 1024 + ks * 128;
    float a0 = 0.f, a1 = 0.f;
    for (int i = 0; i < 128; i += 8) {
        short8 zv = *(const short8*)(z + i);
        #pragma unroll
        for (int j = 0; j < 8; j++) {
            float zf = bf2f(zv[j]);
            a0 += zf * w0[i + j];
            a1 += zf * w1[i + j];
        }
    }
    a0 += __shfl_xor(a0, 1); a0 += __shfl_xor(a0, 2); a0 += __shfl_xor(a0, 4);
    a1 += __shfl_xor(a1, 1); a1 += __shfl_xor(a1, 2); a1 += __shfl_xor(a1, 4);
    if (ks == 0) {
        float p0 = fmaxf(a0 + b3[0], 0.f), p1 = fmaxf(a1 + b3[1], 0.f);
        out[row * 2] = p0; out[row * 2 + 1] = p1;
        float t0 = tgt[row * 2], t1 = tgt[row * 2 + 1];
        ls[wv * 8 + rsub] = (p0 - p0 * t0 + __logf(1.f + __expf(-p0)))
                          + (p1 - p1 * t1 + __logf(1.f + __expf(-p1)));
    }
    __syncthreads();
    if (tid == 0) {
        float s = 0.f;
        for (int i = 0; i < 32; i++) s += ls[i];
        lsum[blockIdx.x] = s;
    }
}

__global__ void k_loss_final(const float* __restrict__ lsum, float* __restrict__ out) {
    int l = threadIdx.x;   // 64 threads
    float v = lsum[l] + lsum[l + 64];
    for (int m = 1; m < 64; m <<= 1) v += __shfl_xor(v, m);
    if (l == 0) out[B_ * 2] = v / (float)(B_ * 2);
}

// ---------------------------------------------------------------- launch
extern "C" void kernel_launch(void* const* d_in, const int* in_sizes, int n_in,
                              void* d_out, int out_size, void* d_ws, size_t ws_size,
                              hipStream_t stream) {
    const float* sfeat = (const float*)d_in[0];
    const float* tfeat = (const float*)d_in[1];
    const float* tmask = (const float*)d_in[2];
    const float* tgt   = (const float*)d_in[3];
    const float* h0    = (const float*)d_in[4];
    const float* c0    = (const float*)d_in[5];
    const float* Wih   = (const float*)d_in[6];
    const float* Whh   = (const float*)d_in[7];
    const float* bih   = (const float*)d_in[8];
    const float* bhh   = (const float*)d_in[9];
    const float* sW1   = (const float*)d_in[10];
    const float* sb1   = (const float*)d_in[11];
    const float* sW2   = (const float*)d_in[12];
    const float* sb2   = (const float*)d_in[13];
    const float* sW3   = (const float*)d_in[14];
    const float* sb3   = (const float*)d_in[15];
    const float* dW1   = (const float*)d_in[16];
    const float* db1   = (const float*)d_in[17];
    const float* dW2   = (const float*)d_in[18];
    const float* db2   = (const float*)d_in[19];
    const float* dW3   = (const float*)d_in[20];
    const float* db3   = (const float*)d_in[21];

    char* ws = (char*)d_ws;
    size_t off = 0;
    short* Whh_bf = (short*)(ws + off); off += (size_t)F_ * GH_ * H_ * 2;       // 25,165,824
    short* dW1_bf = (short*)(ws + off); off += (size_t)1024 * ZW_ * 2;          // 13,107,200
    short* dW2_bf = (short*)(ws + off); off += (size_t)1024 * 1024 * 2;         //  2,097,152
    float* biasb  = (float*)(ws + off); off += (size_t)F_ * GH_ * 4;            //     98,304
    float* sW1T   = (float*)(ws + off); off += (size_t)64 * 256 * 4;
    float* sW2T   = (float*)(ws + off); off += (size_t)256 * 256 * 4;
    float* sW3T   = (float*)(ws + off); off += (size_t)256 * 256 * 4;
    short* Z      = (short*)(ws + off); off += (size_t)B_ * ZW_ * 2;            // 52,428,800
    short* Z1     = (short*)(ws + off); off += (size_t)B_ * 1024 * 2;
    short* Z2     = (short*)(ws + off); off += (size_t)B_ * 1024 * 2;
    float* lsum   = (float*)(ws + off); off += 128 * 4;

    float* out = (float*)d_out;

    k_convert<<<2048, 256, 0, stream>>>(Whh, dW1, dW2, bih, bhh, sW1, sW2, sW3,
                                        Whh_bf, dW1_bf, dW2_bf, biasb, sW1T, sW2T, sW3T);
    k_lstm<<<768, 512, 0, stream>>>(Whh_bf, Wih, biasb, tfeat, tmask, h0, c0, Z);
    k_static<<<4096, 256, 0, stream>>>(sfeat, sW1T, sb1, sW2T, sb2, sW3T, sb3, Z);
    k_gemm_relu<<<dim3(32, 8), 256, 0, stream>>>(Z, dW1_bf, db1, Z1, B_, 1024, ZW_);
    k_gemm_relu<<<dim3(32, 8), 256, 0, stream>>>(Z1, dW2_bf, db2, Z2, B_, 1024, 1024);
    k_head3<<<128, 256, 0, stream>>>(Z2, dW3, db3, tgt, out, lsum);
    k_loss_final<<<1, 64, 0, stream>>>(lsum, out);
}